// Round 2
// baseline (2022.860 us; speedup 1.0000x reference)
//
#include <hip/hip_runtime.h>
#include <cstddef>

#define VOC 23
#define SEQ 256
#define NB  512
#define HID 4096
#define NCOL 11776   // SEQ*2*VOC
#define EPS_TIE 1e-4f

// multiplicative inverses mod 23 (inv[0]=0 sentinel, matches reference table)
__constant__ int INV23[VOC] = {0,1,12,8,6,14,4,10,3,18,7,21,2,16,5,20,13,19,9,17,15,11,22};

// K1: extract token index per (b,l) from exact one-hot input; copy odd rows to out.
__global__ __launch_bounds__(256) void k_tok_copy(const float* __restrict__ in,
                                                  float* __restrict__ out,
                                                  int* __restrict__ tok) {
  const int b = blockIdx.x;
  const int l = threadIdx.x;
  const float* row = in + ((size_t)b * SEQ + l) * VOC;
  int t = 0;
  float best = -1.0f;
#pragma unroll
  for (int v = 0; v < VOC; ++v) {
    float x = row[v];
    if (x > best) { best = x; t = v; }
  }
  tok[b * SEQ + l] = t;
  if (l & 1) {
    float* o = out + ((size_t)b * SEQ + l) * VOC;
#pragma unroll
    for (int v = 0; v < VOC; ++v) o[v] = row[v];
  }
}

// K2: h[b][:] = relu(b1 + sum over odd l of W1[l*23 + tok[b,l], :])
__global__ __launch_bounds__(256) void k_hidden(const float* __restrict__ W1,
                                                const float* __restrict__ b1,
                                                const int* __restrict__ tok,
                                                float* __restrict__ h) {
  const int b = blockIdx.x;
  const int tid = threadIdx.x;
  __shared__ int rowS[128];
  if (tid < 128) {
    const int l = 2 * tid + 1;
    rowS[tid] = l * VOC + tok[b * SEQ + l];
  }
  __syncthreads();
  float4 acc[4];
#pragma unroll
  for (int j = 0; j < 4; ++j) acc[j] = make_float4(0.f, 0.f, 0.f, 0.f);
  for (int i = 0; i < 128; ++i) {
    const float4* wr = (const float4*)(W1 + (size_t)rowS[i] * HID);
#pragma unroll
    for (int j = 0; j < 4; ++j) {
      float4 w = wr[tid + 256 * j];
      acc[j].x += w.x; acc[j].y += w.y; acc[j].z += w.z; acc[j].w += w.w;
    }
  }
  float4* hb = (float4*)(h + (size_t)b * HID);
  const float4* bv = (const float4*)b1;
#pragma unroll
  for (int j = 0; j < 4; ++j) {
    float4 bb = bv[tid + 256 * j];
    float4 r;
    r.x = fmaxf(acc[j].x + bb.x, 0.f);
    r.y = fmaxf(acc[j].y + bb.y, 0.f);
    r.z = fmaxf(acc[j].z + bb.z, 0.f);
    r.w = fmaxf(acc[j].w + bb.w, 0.f);
    hb[tid + 256 * j] = r;
  }
}

// K3: fused GEMM2 (even-position columns only) + argmax (with fp64 tie recheck)
// + modular one-hot write.
__global__ __launch_bounds__(192) void k_net_argmax(const float* __restrict__ h,
                                                    const float* __restrict__ W2,
                                                    const float* __restrict__ b2,
                                                    const int* __restrict__ tok,
                                                    float* __restrict__ out) {
  const int lep = blockIdx.x;        // covers even positions l = 4*lep and 4*lep+2
  const int bbase = blockIdx.y * 128;
  const int tid = threadIdx.x;       // 192

  __shared__ __align__(16) float smem[14592];
  float* HsT = smem;                 // [64 k][132]  (128 m + 4 pad)
  float* Ws  = smem + 8448;          // [64 k][96]

  const int tm = tid & 15;           // m = 8*tm .. 8*tm+7
  const int tc = tid >> 4;           // c = 8*tc .. 8*tc+7  (tc in [0,12))
  const int colbase = 184 * lep;     // W2 column of (l=4*lep, c=0)

  float acc[8][8];
#pragma unroll
  for (int i = 0; i < 8; ++i)
#pragma unroll
    for (int j = 0; j < 8; ++j) acc[i][j] = 0.f;

  for (int k0 = 0; k0 < HID; k0 += 64) {
    __syncthreads();
    for (int idx = tid; idx < 2048; idx += 192) {
      const int m = idx >> 4;
      const int k4 = idx & 15;
      float4 v = *(const float4*)(h + (size_t)(bbase + m) * HID + k0 + 4 * k4);
      HsT[(4 * k4 + 0) * 132 + m] = v.x;
      HsT[(4 * k4 + 1) * 132 + m] = v.y;
      HsT[(4 * k4 + 2) * 132 + m] = v.z;
      HsT[(4 * k4 + 3) * 132 + m] = v.w;
    }
    for (int idx = tid; idx < 6144; idx += 192) {
      const int j = idx / 96;
      const int c = idx - j * 96;
      float val = 0.f;
      if (c < 92) {
        const int col = colbase + c + (c >= 46 ? 46 : 0);
        val = W2[(size_t)(k0 + j) * NCOL + col];
      }
      Ws[idx] = val;
    }
    __syncthreads();
    for (int k = 0; k < 64; ++k) {
      const float* hp = HsT + k * 132 + 8 * tm;
      const float* wp = Ws + k * 96 + 8 * tc;
      float4 h0 = *(const float4*)(hp);
      float4 h1 = *(const float4*)(hp + 4);
      float4 w0 = *(const float4*)(wp);
      float4 w1 = *(const float4*)(wp + 4);
      float hh[8] = {h0.x, h0.y, h0.z, h0.w, h1.x, h1.y, h1.z, h1.w};
      float ww[8] = {w0.x, w0.y, w0.z, w0.w, w1.x, w1.y, w1.z, w1.w};
#pragma unroll
      for (int i = 0; i < 8; ++i)
#pragma unroll
        for (int j = 0; j < 8; ++j)
          acc[i][j] = fmaf(hh[i], ww[j], acc[i][j]);
    }
  }
  __syncthreads();
  // netS[m][96] + scratch regions for tie recheck
  float* netS = smem;                    // 12288 floats
  float* spare = smem + 12288;           // 2304 floats
  int* locS = (int*)spare;               // [256] (m*2+p)
  int* scS  = (int*)(spare + 256);       // [256]
  int* cntS = (int*)(spare + 512);       // [1]
  int* list = (int*)(spare + 513);       // [512]
  double* dpart = (double*)(spare + 1028); // [184] (8-byte aligned)
  double* dlog  = (double*)(spare + 1398); // [23]

  if (tid == 0) *cntS = 0;
#pragma unroll
  for (int i = 0; i < 8; ++i)
#pragma unroll
    for (int j = 0; j < 8; ++j)
      netS[(8 * tm + i) * 96 + 8 * tc + j] = acc[i][j];
  __syncthreads();

  // first-pass fp32 argmax + near-tie flagging
  if (tid < 128) {
    const int m = tid;
#pragma unroll
    for (int p = 0; p < 2; ++p) {
      const int l = 4 * lep + 2 * p;
      const float* nrow = netS + m * 96 + p * 46;
      const float* bp = b2 + l * 46;
#pragma unroll
      for (int grp = 0; grp < 2; ++grp) {
        float b0 = -1e30f, b1v = -1e30f; int bi = 0;
        for (int c = 0; c < VOC; ++c) {
          float x = nrow[grp * VOC + c] + bp[grp * VOC + c];
          if (x > b0) { b1v = b0; b0 = x; bi = c; }
          else if (x > b1v) b1v = x;
        }
        if (grp == 0) locS[m * 2 + p] = bi; else scS[m * 2 + p] = bi;
        if (b0 - b1v < EPS_TIE) {
          int slot = atomicAdd(cntS, 1);
          list[slot] = m | (p << 8) | (grp << 9);
        }
      }
    }
  }
  __syncthreads();

  // cooperative fp64 recheck of flagged argmaxes
  const int nflag = *cntS;
  for (int e = 0; e < nflag; ++e) {
    const int ent = list[e];
    const int m = ent & 255, p = (ent >> 8) & 1, grp = (ent >> 9) & 1;
    const int b = bbase + m;
    const int l = 4 * lep + 2 * p;
    const int col0 = l * 46 + grp * VOC;
    if (tid < 184) {
      const int c = tid >> 3;
      const int part = tid & 7;
      const float* hb = h + (size_t)b * HID;
      const size_t colc = (size_t)(col0 + c);
      double s0 = 0, s1 = 0, s2 = 0, s3 = 0;
      int k = part * 512;
      for (int kk = 0; kk < 512; kk += 4, k += 4) {
        s0 += (double)hb[k]     * (double)W2[(size_t)(k)     * NCOL + colc];
        s1 += (double)hb[k + 1] * (double)W2[(size_t)(k + 1) * NCOL + colc];
        s2 += (double)hb[k + 2] * (double)W2[(size_t)(k + 2) * NCOL + colc];
        s3 += (double)hb[k + 3] * (double)W2[(size_t)(k + 3) * NCOL + colc];
      }
      dpart[tid] = (s0 + s1) + (s2 + s3);
    }
    __syncthreads();
    if (tid < VOC) {
      double s = (double)b2[col0 + tid];
      for (int q = 0; q < 8; ++q) s += dpart[tid * 8 + q];
      dlog[tid] = s;
    }
    __syncthreads();
    if (tid == 0) {
      double best = -1e300; int bi = 0;
      for (int c = 0; c < VOC; ++c) {
        if (dlog[c] > best) { best = dlog[c]; bi = c; }
      }
      if (grp == 0) locS[m * 2 + p] = bi; else scS[m * 2 + p] = bi;
    }
    __syncthreads();
  }

  // final modular one-hot write
  if (tid < 128) {
    const int m = tid;
    const int b = bbase + m;
#pragma unroll
    for (int p = 0; p < 2; ++p) {
      const int l = 4 * lep + 2 * p;
      const int loc = locS[m * 2 + p];
      const int sc  = scS[m * 2 + p];
      float* o = out + ((size_t)b * SEQ + l) * VOC;
      if (sc == 0) {
        for (int v = 0; v < VOC; ++v) o[v] = 0.f;
      } else {
        const int t = tok[b * SEQ + l];
        int d = t - loc;
        if (d < 0) d += VOC;
        const int u = (INV23[sc] * d) % VOC;
        for (int v = 0; v < VOC; ++v) o[v] = (v == u) ? 1.f : 0.f;
      }
    }
  }
}

extern "C" void kernel_launch(void* const* d_in, const int* in_sizes, int n_in,
                              void* d_out, int out_size, void* d_ws, size_t ws_size,
                              hipStream_t stream) {
  const float* in  = (const float*)d_in[0];
  // d_in[1] = mask: fixed (l%2) pattern, hardcoded in the kernels
  const float* W1  = (const float*)d_in[2];
  const float* b1  = (const float*)d_in[3];
  const float* W2  = (const float*)d_in[4];
  const float* b2  = (const float*)d_in[5];
  float* out = (float*)d_out;

  int*   tok = (int*)d_ws;                                             // 512*256 ints
  float* h   = (float*)((char*)d_ws + (size_t)NB * SEQ * sizeof(int)); // 512*4096 f32

  k_tok_copy<<<dim3(NB), dim3(256), 0, stream>>>(in, out, tok);
  k_hidden<<<dim3(NB), dim3(256), 0, stream>>>(W1, b1, tok, h);
  k_net_argmax<<<dim3(64, 4), dim3(192), 0, stream>>>(h, W2, b2, tok, out);
}

// Round 3
// 1474.711 us; speedup vs baseline: 1.3717x; 1.3717x over previous
//
#include <hip/hip_runtime.h>
#include <cstddef>

#define VOC 23
#define SEQ 256
#define NB  512
#define HID 4096
#define NCOL 11776   // SEQ*2*VOC
#define EPS_TIE 1e-4f

// multiplicative inverses mod 23 (inv[0]=0 sentinel, matches reference table)
__constant__ int INV23[VOC] = {0,1,12,8,6,14,4,10,3,18,7,21,2,16,5,20,13,19,9,17,15,11,22};

// K1: extract token index per (b,l) from exact one-hot input; copy odd rows to out.
__global__ __launch_bounds__(256) void k_tok_copy(const float* __restrict__ in,
                                                  float* __restrict__ out,
                                                  int* __restrict__ tok) {
  const int b = blockIdx.x;
  const int l = threadIdx.x;
  const float* row = in + ((size_t)b * SEQ + l) * VOC;
  int t = 0;
  float best = -1.0f;
#pragma unroll
  for (int v = 0; v < VOC; ++v) {
    float x = row[v];
    if (x > best) { best = x; t = v; }
  }
  tok[b * SEQ + l] = t;
  if (l & 1) {
    float* o = out + ((size_t)b * SEQ + l) * VOC;
#pragma unroll
    for (int v = 0; v < VOC; ++v) o[v] = row[v];
  }
}

// K2: h[b][:] = relu(b1 + sum over odd l of W1[l*23 + tok[b,l], :])
// NOTE: accumulation ORDER must stay identical across rounds (sequential i),
// so the fp64 tie-recheck sees the same h and reproduces round-2's exact pass.
__global__ __launch_bounds__(256) void k_hidden(const float* __restrict__ W1,
                                                const float* __restrict__ b1,
                                                const int* __restrict__ tok,
                                                float* __restrict__ h) {
  const int b = blockIdx.x;
  const int tid = threadIdx.x;
  __shared__ int rowS[128];
  if (tid < 128) {
    const int l = 2 * tid + 1;
    rowS[tid] = l * VOC + tok[b * SEQ + l];
  }
  __syncthreads();
  float4 acc[4];
#pragma unroll
  for (int j = 0; j < 4; ++j) acc[j] = make_float4(0.f, 0.f, 0.f, 0.f);
  for (int i = 0; i < 128; i += 2) {
    const float4* wr0 = (const float4*)(W1 + (size_t)rowS[i] * HID);
    const float4* wr1 = (const float4*)(W1 + (size_t)rowS[i + 1] * HID);
    float4 w0[4], w1[4];
#pragma unroll
    for (int j = 0; j < 4; ++j) w0[j] = wr0[tid + 256 * j];
#pragma unroll
    for (int j = 0; j < 4; ++j) w1[j] = wr1[tid + 256 * j];
#pragma unroll
    for (int j = 0; j < 4; ++j) {
      // keep order: += row_i first, then row_{i+1}
      acc[j].x += w0[j].x; acc[j].y += w0[j].y; acc[j].z += w0[j].z; acc[j].w += w0[j].w;
      acc[j].x += w1[j].x; acc[j].y += w1[j].y; acc[j].z += w1[j].z; acc[j].w += w1[j].w;
    }
  }
  float4* hb = (float4*)(h + (size_t)b * HID);
  const float4* bv = (const float4*)b1;
#pragma unroll
  for (int j = 0; j < 4; ++j) {
    float4 bb = bv[tid + 256 * j];
    float4 r;
    r.x = fmaxf(acc[j].x + bb.x, 0.f);
    r.y = fmaxf(acc[j].y + bb.y, 0.f);
    r.z = fmaxf(acc[j].z + bb.z, 0.f);
    r.w = fmaxf(acc[j].w + bb.w, 0.f);
    hb[tid + 256 * j] = r;
  }
}

// K3 v2: fused GEMM2 (even-position columns only) + argmax (fp64 tie recheck)
// + modular one-hot write.
// Tile: BM=64 batches x 96 cols (2 even positions x 46 logits, +4 pad), BK=64.
// Grid 64x8 = 512 blocks x 256 threads -> 2 blocks/CU, 8 waves/CU.
// Per-thread 4m x 6c register tile; A-reads tc-broadcast, B-reads tm-broadcast.
__global__ __launch_bounds__(256) void k_net_argmax(const float* __restrict__ h,
                                                    const float* __restrict__ W2,
                                                    const float* __restrict__ b2,
                                                    const int* __restrict__ tok,
                                                    float* __restrict__ out) {
  const int bn = blockIdx.x;         // covers even positions l = 4*bn and 4*bn+2
  const int bbase = blockIdx.y * 64;
  const int tid = threadIdx.x;       // 256

  __shared__ __align__(16) float smem[10496];
  float* As = smem;                  // [64 k][68]  (64 m + 4 pad)
  float* Bs = smem + 4352;           // [64 k][96]

  const int tm = tid & 15;           // m = 4*tm .. 4*tm+3
  const int tc = tid >> 4;           // c = 6*tc .. 6*tc+5
  const int colbase = 184 * bn;      // W2 column of (l=4*bn, c=0)

  float acc[4][6];
#pragma unroll
  for (int i = 0; i < 4; ++i)
#pragma unroll
    for (int j = 0; j < 6; ++j) acc[i][j] = 0.f;

  for (int k0 = 0; k0 < HID; k0 += 64) {
    __syncthreads();
    // stage A: h[bbase..+64][k0..k0+64] transposed -> As[k][m]
    {
      int idx = tid;
#pragma unroll
      for (int r = 0; r < 4; ++r, idx += 256) {
        const int k4 = idx & 15;
        const int m = idx >> 4;
        float4 v = *(const float4*)(h + (size_t)(bbase + m) * HID + k0 + 4 * k4);
        As[(4 * k4 + 0) * 68 + m] = v.x;
        As[(4 * k4 + 1) * 68 + m] = v.y;
        As[(4 * k4 + 2) * 68 + m] = v.z;
        As[(4 * k4 + 3) * 68 + m] = v.w;
      }
    }
    // stage B: W2 rows k0..k0+64, two 46-col groups (l=4bn, 4bn+2), pad to 96
    for (int idx = tid; idx < 6144; idx += 256) {
      const int j = idx / 96;
      const int c = idx - j * 96;
      float val = 0.f;
      if (c < 92) {
        const int col = colbase + c + (c >= 46 ? 46 : 0);
        val = W2[(size_t)(k0 + j) * NCOL + col];
      }
      Bs[idx] = val;
    }
    __syncthreads();
#pragma unroll 8
    for (int k = 0; k < 64; ++k) {
      const float* ap = As + k * 68 + 4 * tm;
      const float* wp = Bs + k * 96 + 6 * tc;
      float4 a = *(const float4*)ap;          // byte 272k+16tm, 16-aligned
      float2 w0 = *(const float2*)(wp);       // byte 384k+24tc, 8-aligned
      float2 w1 = *(const float2*)(wp + 2);
      float2 w2v = *(const float2*)(wp + 4);
      float aa[4] = {a.x, a.y, a.z, a.w};
      float ww[6] = {w0.x, w0.y, w1.x, w1.y, w2v.x, w2v.y};
#pragma unroll
      for (int i = 0; i < 4; ++i)
#pragma unroll
        for (int j = 0; j < 6; ++j)
          acc[i][j] = fmaf(aa[i], ww[j], acc[i][j]);
    }
  }
  __syncthreads();
  // netS[m][96] + scratch for tie recheck
  float* netS = smem;                      // [64][96] = 6144 floats
  float* spare = smem + 6144;
  int* locS = (int*)spare;                 // [128] (m*2+p)
  int* scS  = (int*)(spare + 128);         // [128]
  int* cntS = (int*)(spare + 256);         // [1]
  int* list = (int*)(spare + 257);         // [256]
  double* dpart = (double*)(spare + 514);  // [184]  byte off (6144+514)*4 % 8 == 0
  double* dlog  = (double*)(spare + 882);  // [23]

  if (tid == 0) *cntS = 0;
#pragma unroll
  for (int i = 0; i < 4; ++i)
#pragma unroll
    for (int j = 0; j < 6; ++j)
      netS[(4 * tm + i) * 96 + 6 * tc + j] = acc[i][j];
  __syncthreads();

  // first-pass fp32 argmax + near-tie flagging
  if (tid < 128) {
    const int m = tid >> 1;
    const int p = tid & 1;
    const int l = 4 * bn + 2 * p;
    const float* nrow = netS + m * 96 + p * 46;
    const float* bp = b2 + l * 46;
#pragma unroll
    for (int grp = 0; grp < 2; ++grp) {
      float b0 = -1e30f, b1v = -1e30f; int bi = 0;
      for (int c = 0; c < VOC; ++c) {
        float x = nrow[grp * VOC + c] + bp[grp * VOC + c];
        if (x > b0) { b1v = b0; b0 = x; bi = c; }
        else if (x > b1v) b1v = x;
      }
      if (grp == 0) locS[m * 2 + p] = bi; else scS[m * 2 + p] = bi;
      if (b0 - b1v < EPS_TIE) {
        int slot = atomicAdd(cntS, 1);
        list[slot] = m | (p << 8) | (grp << 9);
      }
    }
  }
  __syncthreads();

  // cooperative fp64 recheck of flagged argmaxes (identical math to round 2)
  const int nflag = *cntS;
  for (int e = 0; e < nflag; ++e) {
    const int ent = list[e];
    const int m = ent & 255, p = (ent >> 8) & 1, grp = (ent >> 9) & 1;
    const int b = bbase + m;
    const int l = 4 * bn + 2 * p;
    const int col0 = l * 46 + grp * VOC;
    if (tid < 184) {
      const int c = tid >> 3;
      const int part = tid & 7;
      const float* hb = h + (size_t)b * HID;
      const size_t colc = (size_t)(col0 + c);
      double s0 = 0, s1 = 0, s2 = 0, s3 = 0;
      int k = part * 512;
      for (int kk = 0; kk < 512; kk += 4, k += 4) {
        s0 += (double)hb[k]     * (double)W2[(size_t)(k)     * NCOL + colc];
        s1 += (double)hb[k + 1] * (double)W2[(size_t)(k + 1) * NCOL + colc];
        s2 += (double)hb[k + 2] * (double)W2[(size_t)(k + 2) * NCOL + colc];
        s3 += (double)hb[k + 3] * (double)W2[(size_t)(k + 3) * NCOL + colc];
      }
      dpart[tid] = (s0 + s1) + (s2 + s3);
    }
    __syncthreads();
    if (tid < VOC) {
      double s = (double)b2[col0 + tid];
      for (int q = 0; q < 8; ++q) s += dpart[tid * 8 + q];
      dlog[tid] = s;
    }
    __syncthreads();
    if (tid == 0) {
      double best = -1e300; int bi = 0;
      for (int c = 0; c < VOC; ++c) {
        if (dlog[c] > best) { best = dlog[c]; bi = c; }
      }
      if (grp == 0) locS[m * 2 + p] = bi; else scS[m * 2 + p] = bi;
    }
    __syncthreads();
  }

  // final modular one-hot write
  if (tid < 128) {
    const int m = tid >> 1;
    const int p = tid & 1;
    const int b = bbase + m;
    const int l = 4 * bn + 2 * p;
    const int loc = locS[m * 2 + p];
    const int sc  = scS[m * 2 + p];
    float* o = out + ((size_t)b * SEQ + l) * VOC;
    if (sc == 0) {
      for (int v = 0; v < VOC; ++v) o[v] = 0.f;
    } else {
      const int t = tok[b * SEQ + l];
      int d = t - loc;
      if (d < 0) d += VOC;
      const int u = (INV23[sc] * d) % VOC;
      for (int v = 0; v < VOC; ++v) o[v] = (v == u) ? 1.f : 0.f;
    }
  }
}

extern "C" void kernel_launch(void* const* d_in, const int* in_sizes, int n_in,
                              void* d_out, int out_size, void* d_ws, size_t ws_size,
                              hipStream_t stream) {
  const float* in  = (const float*)d_in[0];
  // d_in[1] = mask: fixed (l%2) pattern, hardcoded in the kernels
  const float* W1  = (const float*)d_in[2];
  const float* b1  = (const float*)d_in[3];
  const float* W2  = (const float*)d_in[4];
  const float* b2  = (const float*)d_in[5];
  float* out = (float*)d_out;

  int*   tok = (int*)d_ws;                                             // 512*256 ints
  float* h   = (float*)((char*)d_ws + (size_t)NB * SEQ * sizeof(int)); // 512*4096 f32

  k_tok_copy<<<dim3(NB), dim3(256), 0, stream>>>(in, out, tok);
  k_hidden<<<dim3(NB), dim3(256), 0, stream>>>(W1, b1, tok, h);
  k_net_argmax<<<dim3(64, 8), dim3(256), 0, stream>>>(h, W2, b2, tok, out);
}

// Round 4
// 680.845 us; speedup vs baseline: 2.9711x; 2.1660x over previous
//
#include <hip/hip_runtime.h>
#include <cstddef>
#include <cstdint>

#define VOC 23
#define SEQ 256
#define NB  512
#define HID 4096
#define NCOL 11776    // SEQ*2*VOC
#define NPK 5888      // packed even-position cols: 128 * 46
#define KP  12288     // 3 * HID (split-bf16 triplets along K)
#define EPS_TIE 4e-5f // fp32-path net error tail <1e-5 -> 4x margin

__constant__ int INV23[VOC] = {0,1,12,8,6,14,4,10,3,18,7,21,2,16,5,20,13,19,9,17,15,11,22};

typedef __attribute__((ext_vector_type(8))) short short8;
typedef __attribute__((ext_vector_type(4))) float f32x4;

static __device__ __forceinline__ unsigned int f2bf(float f) {
  unsigned int x = __float_as_uint(f);
  return (x + 0x7fffu + ((x >> 16) & 1u)) >> 16;   // RNE, finite inputs
}
static __device__ __forceinline__ float bf2f(unsigned int u) {
  return __uint_as_float(u << 16);
}

#define GL2LDS(g, l) __builtin_amdgcn_global_load_lds(                      \
    (const __attribute__((address_space(1))) unsigned int*)(g),             \
    (__attribute__((address_space(3))) unsigned int*)(l), 16, 0, 0)

// K1: token extraction + odd-row copy
__global__ __launch_bounds__(256) void k_tok_copy(const float* __restrict__ in,
                                                  float* __restrict__ out,
                                                  int* __restrict__ tok) {
  const int b = blockIdx.x;
  const int l = threadIdx.x;
  const float* row = in + ((size_t)b * SEQ + l) * VOC;
  int t = 0; float best = -1.0f;
#pragma unroll
  for (int v = 0; v < VOC; ++v) { float x = row[v]; if (x > best) { best = x; t = v; } }
  tok[b * SEQ + l] = t;
  if (l & 1) {
    float* o = out + ((size_t)b * SEQ + l) * VOC;
#pragma unroll
    for (int v = 0; v < VOC; ++v) o[v] = row[v];
  }
}

// Repack W2 -> Bp bf16 B^T [NPK rows][KP cols], triplets per k: [hi, lo, hi].
// 64x64 (k x j) tile, transpose through LDS.
__global__ __launch_bounds__(256) void k_pack_w2(const float* __restrict__ W2,
                                                 unsigned short* __restrict__ Bp) {
  const int k0 = blockIdx.x * 64;   // 64 k-tiles
  const int j0 = blockIdx.y * 64;   // 92 j-tiles
  const int tid = threadIdx.x;
  __shared__ float T[64 * 65];
#pragma unroll
  for (int it = 0; it < 16; ++it) {
    int idx = it * 256 + tid;
    int k_l = idx >> 6, j_l = idx & 63;
    int j = j0 + j_l;
    int ee = j / 46, cc = j - ee * 46;          // packed j -> W2 col 92e+c
    T[j_l * 65 + k_l] = W2[(size_t)(k0 + k_l) * NCOL + 92 * ee + cc];
  }
  __syncthreads();
  const int j_l = tid >> 2, qt = tid & 3;       // 4 threads per output row
  unsigned int d[24];
#pragma unroll
  for (int pr = 0; pr < 8; ++pr) {              // 8 pairs of k = 16 k-units
    int k_l = qt * 16 + pr * 2;
    float va = T[j_l * 65 + k_l], vb = T[j_l * 65 + k_l + 1];
    unsigned int ha = f2bf(va), la = f2bf(va - bf2f(ha));
    unsigned int hb = f2bf(vb), lb = f2bf(vb - bf2f(hb));
    // elems: ha, la, ha | hb, lb, hb  (B triplet = [Bh, Bl, Bh])
    d[pr * 3 + 0] = ha | (la << 16);
    d[pr * 3 + 1] = ha | (hb << 16);
    d[pr * 3 + 2] = lb | (hb << 16);
  }
  char* dst = ((char*)Bp) + (size_t)(j0 + j_l) * (KP * 2) + 6 * k0 + 96 * qt;
#pragma unroll
  for (int u = 0; u < 6; ++u) {
    uint4 w = make_uint4(d[4 * u], d[4 * u + 1], d[4 * u + 2], d[4 * u + 3]);
    ((uint4*)dst)[u] = w;
  }
}

// K2: h = relu(b1 + sum of 128 gathered W1 rows); also emit Ap bf16 triplets [hi,hi,lo]
__global__ __launch_bounds__(256) void k_hidden(const float* __restrict__ W1,
                                                const float* __restrict__ b1,
                                                const int* __restrict__ tok,
                                                float* __restrict__ h,
                                                unsigned short* __restrict__ Ap) {
  const int b = blockIdx.x;
  const int tid = threadIdx.x;
  __shared__ int rowS[128];
  if (tid < 128) {
    const int l = 2 * tid + 1;
    rowS[tid] = l * VOC + tok[b * SEQ + l];
  }
  __syncthreads();
  float4 acc[4];
#pragma unroll
  for (int j = 0; j < 4; ++j) acc[j] = make_float4(0.f, 0.f, 0.f, 0.f);
  for (int i = 0; i < 128; i += 2) {
    const float4* wr0 = (const float4*)(W1 + (size_t)rowS[i] * HID);
    const float4* wr1 = (const float4*)(W1 + (size_t)rowS[i + 1] * HID);
    float4 w0[4], w1[4];
#pragma unroll
    for (int j = 0; j < 4; ++j) w0[j] = wr0[tid + 256 * j];
#pragma unroll
    for (int j = 0; j < 4; ++j) w1[j] = wr1[tid + 256 * j];
#pragma unroll
    for (int j = 0; j < 4; ++j) {
      acc[j].x += w0[j].x; acc[j].y += w0[j].y; acc[j].z += w0[j].z; acc[j].w += w0[j].w;
      acc[j].x += w1[j].x; acc[j].y += w1[j].y; acc[j].z += w1[j].z; acc[j].w += w1[j].w;
    }
  }
  float4* hb = (float4*)(h + (size_t)b * HID);
  const float4* bv = (const float4*)b1;
#pragma unroll
  for (int j = 0; j < 4; ++j) {
    float4 bb = bv[tid + 256 * j];
    float4 r;
    r.x = fmaxf(acc[j].x + bb.x, 0.f);
    r.y = fmaxf(acc[j].y + bb.y, 0.f);
    r.z = fmaxf(acc[j].z + bb.z, 0.f);
    r.w = fmaxf(acc[j].w + bb.w, 0.f);
    hb[tid + 256 * j] = r;
    // split-bf16 A triplets: per elem [hi, hi, lo]
    unsigned int h0 = f2bf(r.x), L0 = f2bf(r.x - bf2f(h0));
    unsigned int h1 = f2bf(r.y), L1 = f2bf(r.y - bf2f(h1));
    unsigned int h2 = f2bf(r.z), L2 = f2bf(r.z - bf2f(h2));
    unsigned int h3 = f2bf(r.w), L3 = f2bf(r.w - bf2f(h3));
    uint2* ap = (uint2*)(((char*)Ap) + (size_t)b * (KP * 2) + 24 * (tid + 256 * j));
    ap[0] = make_uint2(h0 | (h0 << 16), L0 | (h1 << 16));
    ap[1] = make_uint2(h1 | (L1 << 16), h2 | (h2 << 16));
    ap[2] = make_uint2(L2 | (h3 << 16), h3 | (L3 << 16));
  }
}

// K3: bf16 MFMA GEMM, m97 structure. 128x128 tile, BK=64, split-K=4.
// Grid (46 n-tiles, 4 m-tiles, 4 splits) = 736 blocks, 256 thr (4 waves, 2x2 quadrants).
__global__ __launch_bounds__(256) void k3_mfma(const unsigned short* __restrict__ Ap,
                                               const unsigned short* __restrict__ Bp,
                                               float* __restrict__ partial) {
  __shared__ unsigned short Asm[128 * 64];
  __shared__ unsigned short Bsm[128 * 64];
  const int tid = threadIdx.x;
  const int bn0 = blockIdx.x * 128;
  const int bm0 = blockIdx.y * 128;
  const int s   = blockIdx.z;
  const int lane = tid & 63, wave = tid >> 6;
  const int wm = wave & 1, wn = wave >> 1;
  const int r = lane & 15, q = lane >> 4;

  f32x4 acc[4][4];
#pragma unroll
  for (int i = 0; i < 4; ++i)
#pragma unroll
    for (int j = 0; j < 4; ++j) acc[i][j] = (f32x4){0.f, 0.f, 0.f, 0.f};

  const int kb_base = s * 3072 * 2;   // byte offset into 24576-byte rows
  for (int it = 0; it < 48; ++it) {
    __syncthreads();
    const int kb = kb_base + it * 128;
#pragma unroll
    for (int c2 = 0; c2 < 4; ++c2) {
      const int byte = c2 * 4096 + tid * 16;
      const int row = byte >> 7, col = byte & 127;
      GL2LDS(((const char*)Ap) + (size_t)(bm0 + row) * (KP * 2) + kb + col,
             ((char*)Asm) + byte);
      GL2LDS(((const char*)Bp) + (size_t)(bn0 + row) * (KP * 2) + kb + col,
             ((char*)Bsm) + byte);
    }
    __syncthreads();
#pragma unroll
    for (int kk = 0; kk < 2; ++kk) {
      short8 a[4], bfr[4];
#pragma unroll
      for (int i = 0; i < 4; ++i)
        a[i] = *(const short8*)((const char*)Asm + (64 * wm + 16 * i + r) * 128 + kk * 64 + q * 16);
#pragma unroll
      for (int j = 0; j < 4; ++j)
        bfr[j] = *(const short8*)((const char*)Bsm + (64 * wn + 16 * j + r) * 128 + kk * 64 + q * 16);
#pragma unroll
      for (int i = 0; i < 4; ++i)
#pragma unroll
        for (int j = 0; j < 4; ++j)
          acc[i][j] = __builtin_amdgcn_mfma_f32_16x16x32_bf16(a[i], bfr[j], acc[i][j], 0, 0, 0);
    }
  }
  float* pbase = partial + (size_t)s * NB * NPK;
#pragma unroll
  for (int i = 0; i < 4; ++i) {
    const int m = bm0 + 64 * wm + 16 * i + 4 * q;   // C row = quad*4+reg
#pragma unroll
    for (int j = 0; j < 4; ++j) {
      const int n = bn0 + 64 * wn + 16 * j + r;     // C col = lane&15
      float* pp = pbase + (size_t)m * NPK + n;
#pragma unroll
      for (int reg = 0; reg < 4; ++reg)
        pp[(size_t)reg * NPK] = acc[i][j][reg];
    }
  }
}

// Epilogue: sum 4 partials + b2, argmax both groups, flag ties, write one-hot rows.
__global__ __launch_bounds__(256) void k_epilogue(const float* __restrict__ partial,
                                                  const float* __restrict__ b2,
                                                  const int* __restrict__ tok,
                                                  int* __restrict__ win,
                                                  int* __restrict__ gcnt,
                                                  int* __restrict__ glist,
                                                  float* __restrict__ out) {
  const int b = blockIdx.x, tid = threadIdx.x;
  const int e = tid >> 1, grp = tid & 1;
  __shared__ int winS[256];
  __shared__ int flagS[256];
  float x[VOC];
  const size_t base = (size_t)b * NPK + 46 * e + 23 * grp;
#pragma unroll
  for (int c = 0; c < VOC; ++c) x[c] = b2[92 * e + 23 * grp + c];
#pragma unroll
  for (int s2 = 0; s2 < 4; ++s2) {
    const float* pp = partial + (size_t)s2 * NB * NPK + base;
#pragma unroll
    for (int c = 0; c < VOC; ++c) x[c] += pp[c];
  }
  float b0 = -1e30f, b1v = -1e30f; int bi = 0;
#pragma unroll
  for (int c = 0; c < VOC; ++c) {
    if (x[c] > b0) { b1v = b0; b0 = x[c]; bi = c; }
    else if (x[c] > b1v) b1v = x[c];
  }
  winS[tid] = bi;
  flagS[tid] = (b0 - b1v < EPS_TIE) ? 1 : 0;
  __syncthreads();
  if (!grp) {
    const int loc = winS[tid], sc = winS[tid + 1];
    win[b * 256 + 2 * e] = loc;
    win[b * 256 + 2 * e + 1] = sc;
    const int f0 = flagS[tid], f1 = flagS[tid + 1];
    if (f0 | f1) {
      int idx = atomicAdd(gcnt, 1);
      glist[idx] = e | (b << 7) | (f0 << 16) | (f1 << 17);
    }
    const int l = 2 * e;
    float* o = out + ((size_t)b * SEQ + l) * VOC;
    if (sc == 0) {
      for (int v = 0; v < VOC; ++v) o[v] = 0.f;
    } else {
      const int t = tok[b * SEQ + l];
      int dd = t - loc; if (dd < 0) dd += VOC;
      const int u = (INV23[sc] * dd) % VOC;
      for (int v = 0; v < VOC; ++v) o[v] = (v == u) ? 1.f : 0.f;
    }
  }
}

// fp64 recheck of flagged near-ties, from original fp32 h and W2. Fixed grid.
__global__ __launch_bounds__(192) void k_recheck(const float* __restrict__ h,
                                                 const float* __restrict__ W2,
                                                 const float* __restrict__ b2,
                                                 const int* __restrict__ tok,
                                                 const int* __restrict__ win,
                                                 const int* __restrict__ gcnt,
                                                 const int* __restrict__ glist,
                                                 float* __restrict__ out) {
  const int tid = threadIdx.x;
  __shared__ double dpart[184];
  __shared__ double dlog[VOC];
  __shared__ int decS[2];
  const int n = gcnt[0];
  for (int ei = blockIdx.x; ei < n; ei += 128) {
    const int ent = glist[ei];
    const int e = ent & 127, b = (ent >> 7) & 511;
    const int l = 2 * e;
#pragma unroll
    for (int grp = 0; grp < 2; ++grp) {
      if (!(ent & (1 << (16 + grp)))) {
        if (tid == 0) decS[grp] = win[b * 256 + 2 * e + grp];
      } else {
        const int col0 = 92 * e + 23 * grp;
        if (tid < 184) {
          const int c = tid >> 3, part = tid & 7;
          const float* hb = h + (size_t)b * HID;
          const size_t colc = (size_t)(col0 + c);
          double sacc[8] = {0, 0, 0, 0, 0, 0, 0, 0};
          const int kbase = part * 512;
          for (int kk = 0; kk < 512; kk += 8) {
#pragma unroll
            for (int t2 = 0; t2 < 8; ++t2) {
              const int k = kbase + kk + t2;
              sacc[t2] += (double)hb[k] * (double)W2[(size_t)k * NCOL + colc];
            }
          }
          dpart[tid] = ((sacc[0] + sacc[1]) + (sacc[2] + sacc[3])) +
                       ((sacc[4] + sacc[5]) + (sacc[6] + sacc[7]));
        }
        __syncthreads();
        if (tid < VOC) {
          double sd = (double)b2[col0 + tid];
#pragma unroll
          for (int p2 = 0; p2 < 8; ++p2) sd += dpart[tid * 8 + p2];
          dlog[tid] = sd;
        }
        __syncthreads();
        if (tid == 0) {
          double best = -1e300; int bi2 = 0;
#pragma unroll
          for (int c = 0; c < VOC; ++c)
            if (dlog[c] > best) { best = dlog[c]; bi2 = c; }
          decS[grp] = bi2;
        }
      }
      __syncthreads();
    }
    if (tid < VOC) {
      const int loc = decS[0], sc = decS[1];
      float val = 0.f;
      if (sc != 0) {
        const int t = tok[b * SEQ + l];
        int dd = t - loc; if (dd < 0) dd += VOC;
        const int u = (INV23[sc] * dd) % VOC;
        val = (tid == u) ? 1.f : 0.f;
      }
      out[((size_t)b * SEQ + l) * VOC + tid] = val;
    }
    __syncthreads();
  }
}

extern "C" void kernel_launch(void* const* d_in, const int* in_sizes, int n_in,
                              void* d_out, int out_size, void* d_ws, size_t ws_size,
                              hipStream_t stream) {
  const float* in  = (const float*)d_in[0];
  const float* W1  = (const float*)d_in[2];
  const float* b1  = (const float*)d_in[3];
  const float* W2  = (const float*)d_in[4];
  const float* b2  = (const float*)d_in[5];
  float* out = (float*)d_out;

  char* w = (char*)d_ws;
  int* tok = (int*)w;                         w += (size_t)NB * SEQ * 4;          // 0.5 MB
  float* h = (float*)w;                       w += (size_t)NB * HID * 4;          // 8 MB
  unsigned short* Ap = (unsigned short*)w;    w += (size_t)NB * KP * 2;           // 12.6 MB
  unsigned short* Bp = (unsigned short*)w;    w += (size_t)NPK * KP * 2;          // 144.7 MB
  float* partial = (float*)w;                 w += (size_t)4 * NB * NPK * 4;      // 48.2 MB
  int* win = (int*)w;                         w += (size_t)NB * 256 * 4;          // 0.5 MB
  int* gcnt = (int*)w;                        w += 256;
  int* glist = (int*)w;                       w += (size_t)65536 * 4;             // 0.26 MB

  k_tok_copy<<<dim3(NB), dim3(256), 0, stream>>>(in, out, tok);
  k_pack_w2<<<dim3(64, 92), dim3(256), 0, stream>>>(W2, Bp);
  k_hidden<<<dim3(NB), dim3(256), 0, stream>>>(W1, b1, tok, h, Ap);
  hipMemsetAsync(gcnt, 0, 4, stream);
  k3_mfma<<<dim3(46, 4, 4), dim3(256), 0, stream>>>(Ap, Bp, partial);
  k_epilogue<<<dim3(NB), dim3(256), 0, stream>>>(partial, b2, tok, win, gcnt, glist, out);
  k_recheck<<<dim3(128), dim3(192), 0, stream>>>(h, W2, b2, tok, win, gcnt, glist, out);
}